// Round 2
// baseline (606.949 us; speedup 1.0000x reference)
//
#include <hip/hip_runtime.h>
#include <hip/hip_bf16.h>

typedef __bf16 bf16x8 __attribute__((ext_vector_type(8)));
typedef float f32x4 __attribute__((ext_vector_type(4)));

#define KDIM 512
#define NDIM 1024
#define DDIM 256
#define TDIM 512
#define MDIM 2048
#define NROWS 16384          // B*T type_flat rows
#define NEGV -1e10f

__device__ __forceinline__ unsigned short f2b(float f) {
    unsigned int u = __builtin_bit_cast(unsigned int, f);
    u += 0x7fffu + ((u >> 16) & 1u);   // RNE
    return (unsigned short)(u >> 16);
}
__device__ __forceinline__ float b2f(unsigned short u) {
    unsigned int x = ((unsigned int)u) << 16;
    return __builtin_bit_cast(float, x);
}

// ---------------------------------------------------------------------------
// prep: type_flat (k=0 slices of token_reprs, f32) -> bf16 [16384][256]
// ---------------------------------------------------------------------------
__global__ void prep_tok(const float* __restrict__ tok,
                         unsigned short* __restrict__ tfb) {
    int g = (blockIdx.x * 256 + threadIdx.x) * 4;   // 4 elems/thread
    int i = g >> 8;          // type_flat row
    int c = g & 255;         // col
    float4 v = *(const float4*)(tok + (size_t)i * 1024 + c);
    tfb[g + 0] = f2b(v.x);
    tfb[g + 1] = f2b(v.y);
    tfb[g + 2] = f2b(v.z);
    tfb[g + 3] = f2b(v.w);
}

// ---------------------------------------------------------------------------
// prep: Wg, Wv f32 [k][n] -> bf16 transposed [n][k]
// ---------------------------------------------------------------------------
__global__ void prep_w(const float* __restrict__ Wg,
                       const float* __restrict__ Wv,
                       unsigned short* __restrict__ wgT,
                       unsigned short* __restrict__ wvT) {
    int idx = blockIdx.x * 256 + threadIdx.x;   // 524288
    int n = idx >> 9;
    int k = idx & 511;
    int src = k * NDIM + n;
    wgT[idx] = f2b(Wg[src]);
    wvT[idx] = f2b(Wv[src]);
}

// ---------------------------------------------------------------------------
// lemmas: fused gather + dual GEMM (x@Wg, x@Wv) + silu(G)*V @ Wo row-reduce.
// 128 edges x 128 n per workgroup; n-loop inside block so the Wo reduction
// stays in registers. 4 waves, each 64x64 via 4x4 mfma_f32_16x16x32_bf16.
// BK=64, LDS pad +8 (2-way conflict only = free, m136).
// ---------------------------------------------------------------------------
__launch_bounds__(256, 2)
__global__ void lemma_gemm(const unsigned short* __restrict__ tfb,
                           const unsigned short* __restrict__ wgT,
                           const unsigned short* __restrict__ wvT,
                           const float* __restrict__ Wo,
                           const int* __restrict__ scope,
                           const int* __restrict__ goal,
                           float* __restrict__ outLem,
                           int E) {
    constexpr int ET = 128, NT = 128, KC = 64, LDK = KC + 8;
    __shared__ unsigned short sA[ET * LDK];
    __shared__ unsigned short sBg[NT * LDK];
    __shared__ unsigned short sBv[NT * LDK];
    __shared__ int sScope[ET];
    __shared__ int sGoal[ET];
    __shared__ float sRed[2 * ET];

    const int tid = threadIdx.x;
    const int lane = tid & 63;
    const int w = tid >> 6;
    const int wm = w & 1;
    const int wn = w >> 1;
    const int col = lane & 15;
    const int q = lane >> 4;
    const int etile = blockIdx.x * ET;

    if (tid < ET) {
        int e = etile + tid;
        sScope[tid] = (e < E) ? scope[e] : 0;
        sGoal[tid]  = (e < E) ? goal[e] : 0;
    }

    float lem[16];
#pragma unroll
    for (int i = 0; i < 16; i++) lem[i] = 0.f;

    for (int nt = 0; nt < NDIM / NT; nt++) {
        const int n0 = nt * NT;
        f32x4 accG[4][4], accV[4][4];
#pragma unroll
        for (int mi = 0; mi < 4; mi++)
#pragma unroll
            for (int ni = 0; ni < 4; ni++) {
                accG[mi][ni] = (f32x4){0.f, 0.f, 0.f, 0.f};
                accV[mi][ni] = (f32x4){0.f, 0.f, 0.f, 0.f};
            }
        for (int kc = 0; kc < KDIM / KC; kc++) {
            const int k0 = kc * KC;
            __syncthreads();
            // A tile: 128 rows x 64 k. k<256 -> scope row, k>=256 -> goal row.
#pragma unroll
            for (int it = 0; it < 4; it++) {
                int u = it * 256 + tid;             // 1024 x 16B units
                int row = u >> 3, c16 = u & 7;
                int id = (k0 < 256) ? sScope[row] : sGoal[row];
                const unsigned short* src =
                    tfb + (size_t)id * DDIM + (k0 & 255) + c16 * 8;
                *(uint4*)(&sA[row * LDK + c16 * 8]) = *(const uint4*)src;
            }
            // B tiles (bf16 W^T rows contiguous in k)
#pragma unroll
            for (int it = 0; it < 4; it++) {
                int u = it * 256 + tid;
                int row = u >> 3, c16 = u & 7;
                size_t off = (size_t)(n0 + row) * KDIM + k0 + c16 * 8;
                *(uint4*)(&sBg[row * LDK + c16 * 8]) = *(const uint4*)(wgT + off);
                *(uint4*)(&sBv[row * LDK + c16 * 8]) = *(const uint4*)(wvT + off);
            }
            __syncthreads();
#pragma unroll
            for (int kk = 0; kk < KC; kk += 32) {
                bf16x8 af[4], bg[4], bv[4];
#pragma unroll
                for (int mi = 0; mi < 4; mi++)
                    af[mi] = __builtin_bit_cast(bf16x8,
                        *(const uint4*)(&sA[(wm * 64 + mi * 16 + col) * LDK + kk + q * 8]));
#pragma unroll
                for (int ni = 0; ni < 4; ni++) {
                    bg[ni] = __builtin_bit_cast(bf16x8,
                        *(const uint4*)(&sBg[(wn * 64 + ni * 16 + col) * LDK + kk + q * 8]));
                    bv[ni] = __builtin_bit_cast(bf16x8,
                        *(const uint4*)(&sBv[(wn * 64 + ni * 16 + col) * LDK + kk + q * 8]));
                }
#pragma unroll
                for (int mi = 0; mi < 4; mi++)
#pragma unroll
                    for (int ni = 0; ni < 4; ni++) {
                        accG[mi][ni] = __builtin_amdgcn_mfma_f32_16x16x32_bf16(
                            af[mi], bg[ni], accG[mi][ni], 0, 0, 0);
                        accV[mi][ni] = __builtin_amdgcn_mfma_f32_16x16x32_bf16(
                            af[mi], bv[ni], accV[mi][ni], 0, 0, 0);
                    }
            }
        }
        // epilogue: lem += silu(G) * V * Wo[n]. C/D: M=q*4+r, N=col (m89).
#pragma unroll
        for (int ni = 0; ni < 4; ni++) {
            float wo = Wo[n0 + wn * 64 + ni * 16 + col];
#pragma unroll
            for (int mi = 0; mi < 4; mi++)
#pragma unroll
                for (int r = 0; r < 4; r++) {
                    float g = accG[mi][ni][r];
                    float v = accV[mi][ni][r];
                    float s = g / (1.f + __expf(-g));
                    lem[mi * 4 + r] += s * v * wo;
                }
        }
    }
    // reduce across 16 cols (N), then across the 2 n-waves via LDS
#pragma unroll
    for (int i = 0; i < 16; i++) {
        float v = lem[i];
        for (int off = 8; off > 0; off >>= 1) v += __shfl_xor(v, off, 16);
        if (col == 0) {
            int row = wm * 64 + (i >> 2) * 16 + q * 4 + (i & 3);
            sRed[wn * ET + row] = v;
        }
    }
    __syncthreads();
    if (tid < ET) {
        int e = etile + tid;
        if (e < E) outLem[e] = sRed[tid] + sRed[ET + tid];
    }
}

// ---------------------------------------------------------------------------
// lm_preds[m,t] = dot(mask_row[m], type_reprs[bp[m], t]), masked.
// One block per m; 4 waves; wave handles t stepping by 4. Lane's 4 mask
// values live in registers (loaded once). Coalesced float4 candidate reads.
// ---------------------------------------------------------------------------
__global__ void lm_preds_kernel(const float* __restrict__ tok,
                                const int* __restrict__ lm_indices,
                                const int* __restrict__ batch_pointers,
                                const int* __restrict__ tpm,
                                float* __restrict__ outP) {
    const int m = blockIdx.x;
    const int tid = threadIdx.x;
    const int lane = tid & 63;
    const int w = tid >> 6;
    const int b = batch_pointers[m];
    // mask row: token_reprs.reshape(-1, D)[lmi[m]] -> contiguous 256 floats
    float4 mk = *(const float4*)(tok + (size_t)lm_indices[m] * DDIM + lane * 4);
    const float* cand = tok + (size_t)b * TDIM * 1024;   // (b, t, 0, :) rows, stride 1024
    const int* pm = tpm + b * TDIM;
    for (int t = w; t < TDIM; t += 4) {
        float4 c = *(const float4*)(cand + (size_t)t * 1024 + lane * 4);
        float acc = c.x * mk.x + c.y * mk.y + c.z * mk.z + c.w * mk.w;
#pragma unroll
        for (int off = 32; off > 0; off >>= 1) acc += __shfl_xor(acc, off, 64);
        if (lane == 0) outP[(size_t)m * TDIM + t] = pm[t] ? acc : NEGV;
    }
}

extern "C" void kernel_launch(void* const* d_in, const int* in_sizes, int n_in,
                              void* d_out, int out_size, void* d_ws, size_t ws_size,
                              hipStream_t stream) {
    const float* tok = (const float*)d_in[0];
    const float* Wg  = (const float*)d_in[1];
    const float* Wv  = (const float*)d_in[2];
    const float* Wo  = (const float*)d_in[3];
    const int* edge = (const int*)d_in[4];
    const int* lmi  = (const int*)d_in[5];
    const int* bp   = (const int*)d_in[6];
    const int* tpm  = (const int*)d_in[7];
    const int E = in_sizes[4] / 2;           // 100000
    float* out = (float*)d_out;

    unsigned short* tfb = (unsigned short*)d_ws;              // 16384*256 bf16 = 8 MB
    unsigned short* wgT = tfb + (size_t)NROWS * DDIM;         // 1 MB
    unsigned short* wvT = wgT + (size_t)KDIM * NDIM;          // 1 MB

    prep_tok<<<dim3((NROWS * DDIM) / 1024), dim3(256), 0, stream>>>(tok, tfb);
    prep_w<<<dim3((KDIM * NDIM) / 256), dim3(256), 0, stream>>>(Wg, Wv, wgT, wvT);
    lemma_gemm<<<dim3((E + 127) / 128), dim3(256), 0, stream>>>(
        tfb, wgT, wvT, Wo, edge, edge + E, out, E);
    lm_preds_kernel<<<dim3(MDIM), dim3(256), 0, stream>>>(
        tok, lmi, bp, tpm, out + E);
}